// Round 6
// baseline (306.340 us; speedup 1.0000x reference)
//
#include <hip/hip_runtime.h>
#include <math.h>

typedef __attribute__((ext_vector_type(4))) float f32x4;
typedef __attribute__((ext_vector_type(8))) short s16x8;
typedef __attribute__((ext_vector_type(4))) short s16x4;
typedef unsigned short ushort_t;

#define HW   1024
#define C_IN 768
#define B_N  8

__device__ inline ushort_t f2bf(float f) {
    unsigned u = __builtin_bit_cast(unsigned, f);
    unsigned r = u + 0x7FFFu + ((u >> 16) & 1u);
    return (ushort_t)(r >> 16);
}
__device__ inline float bf2f(short s) {
    return __builtin_bit_cast(float, ((unsigned)(ushort_t)s) << 16);
}

// ---------------------------------------------------------------------------
// x [b][c][pos] fp32  ->  xt [b][pos][c] bf16   (row = 768 ch = 1536 B)
// ---------------------------------------------------------------------------
__global__ __launch_bounds__(256) void prepack_xt(
    const float* __restrict__ x, ushort_t* __restrict__ xt)
{
    __shared__ ushort_t tile[64][66];
    int bid = blockIdx.x;                 // 8 * 12 * 16
    int b  = bid / 192;
    int r  = bid % 192;
    int cg = r / 16, pg = r % 16;
    int c0 = cg * 64, p0 = pg * 64;
    int t = threadIdx.x;
#pragma unroll
    for (int i = 0; i < 16; ++i) {
        int idx = t + i * 256;
        int cr = idx >> 6, col = idx & 63;
        tile[cr][col] = f2bf(x[(((size_t)b * C_IN + c0 + cr) << 10) + p0 + col]);
    }
    __syncthreads();
#pragma unroll
    for (int i = 0; i < 16; ++i) {
        int idx = t + i * 256;
        int pr = idx >> 6, col = idx & 63;
        xt[((size_t)(b << 10) + p0 + pr) * C_IN + c0 + col] = tile[col][pr];
    }
}

// ---------------------------------------------------------------------------
// proj_w -> MFMA A-frag layout, k = tap*768 + c (tap-major).
// ---------------------------------------------------------------------------
__global__ __launch_bounds__(256) void prepack_proj(
    const float* __restrict__ pw, ushort_t* __restrict__ A)
{
    int t = blockIdx.x * 256 + threadIdx.x;     // 216*48*64 threads
    int lane = t & 63;
    int smi  = t >> 6;
    int s  = smi / 48, mf = smi - s * 48;
    int o  = mf * 16 + (lane & 15);
    int k0 = s * 32 + ((lane >> 4) << 3);
    int tap = k0 / 768;
    int c   = k0 - tap * 768;
    const float* src = pw + (size_t)o * 6912 + (size_t)c * 9 + tap;
    s16x8 pk;
#pragma unroll
    for (int e = 0; e < 8; ++e) pk[e] = (short)f2bf(src[e * 9]);
    *(s16x8*)(A + (size_t)smi * 512 + lane * 8) = pk;
}

__global__ __launch_bounds__(256) void prepack_om(
    const float* __restrict__ offw, const float* __restrict__ mskw,
    ushort_t* __restrict__ A2)
{
    int t = blockIdx.x * 256 + threadIdx.x;     // 216*2*64 threads
    int lane = t & 63;
    int smi  = t >> 6;
    int s  = smi >> 1, mf = smi & 1;
    int oc = mf * 16 + (lane & 15);
    int k0 = s * 32 + ((lane >> 4) << 3);
    int tap = k0 / 768;
    int c   = k0 - tap * 768;
    s16x8 pk;
#pragma unroll
    for (int e = 0; e < 8; ++e) pk[e] = 0;
    if (oc < 27) {
        const float* src = (oc < 18)
            ? offw + ((size_t)oc        * 768 + c) * 9 + tap
            : mskw + ((size_t)(oc - 18) * 768 + c) * 9 + tap;
#pragma unroll
        for (int e = 0; e < 8; ++e) pk[e] = (short)f2bf(src[e * 9]);
    }
    *(s16x8*)(A2 + (size_t)smi * 512 + lane * 8) = pk;
}

// ---------------------------------------------------------------------------
// Offset/mask conv: LDS-free MFMA GEMM. B-frags are 16B contiguous in xt.
// ---------------------------------------------------------------------------
__global__ __launch_bounds__(256) void offmask_mfma(
    const ushort_t* __restrict__ xt, const ushort_t* __restrict__ A2,
    const float* __restrict__ offb, const float* __restrict__ mbias,
    float* __restrict__ offs, float* __restrict__ maskb)
{
    int bid = blockIdx.x;               // b*32 + pt
    int b = bid >> 5, pt = bid & 31;
    int p0 = pt << 5;
    int t = threadIdx.x, lane = t & 63, wv = t >> 6;
    int mf = wv >> 1, nf = wv & 1;
    int q = lane >> 4;
    int px = p0 + nf * 16 + (lane & 15);
    int h = px >> 5, w = px & 31;
    const char* xb = (const char*)xt + (size_t)b * (HW * 1536);
    f32x4 acc = (f32x4){0.f, 0.f, 0.f, 0.f};

    for (int tap = 0; tap < 9; ++tap) {
        int yy = h + tap / 3 - 1, xx = w + tap % 3 - 1;
        bool ok = (yy >= 0 && yy < 32 && xx >= 0 && xx < 32);
        int pos = ok ? (yy * 32 + xx) : 0;
        const char* bp = xb + (size_t)pos * 1536 + q * 16;
        for (int cs = 0; cs < 24; ++cs) {
            int s = tap * 24 + cs;
            s16x8 bf;
            if (ok) bf = *(const s16x8*)(bp + cs * 64);
            else    bf = (s16x8){0, 0, 0, 0, 0, 0, 0, 0};
            s16x8 af = *(const s16x8*)(A2 + ((size_t)(s * 2 + mf) * 64 + lane) * 8);
            acc = __builtin_amdgcn_mfma_f32_16x16x32_bf16(af, bf, acc, 0, 0, 0);
        }
    }
#pragma unroll
    for (int r = 0; r < 4; ++r) {
        int oc = mf * 16 + ((lane >> 4) << 2) + r;
        if (oc < 18) {
            float v = acc[r] + offb[oc];
            v = fminf(fmaxf(v, -8.f), 8.f);        // max_off = 32//4
            offs[((b * 18 + oc) << 10) + px] = v;
        } else if (oc < 27) {
            float v = acc[r] + mbias[oc - 18];
            maskb[((b * 9 + oc - 18) << 10) + px] = 2.f / (1.f + expf(-v));
        }
    }
}

// ---------------------------------------------------------------------------
// Deformable conv GEMM, tile 384(o) x 64(px), 1024 threads / 16 waves
// (8 wm x 2 wn), 256 blocks = 1/CU. Build replication over o-tiles: 2x
// (was 4x) -> half the gather traffic + half the build VALU per CU.
// Build map: 16 threads per pixel, each covering 4 channels (8B gathers,
// 128B contiguous per pixel-neighbor). Depth-2 gather prefetch, weak
// barriers (lgkmcnt(0)+s_barrier; vmcnt stays in flight), XOR chunk swizzle.
// ---------------------------------------------------------------------------
__global__ __launch_bounds__(1024, 4) void deform_mfma(
    const ushort_t* __restrict__ xt, const ushort_t* __restrict__ Amat,
    const float* __restrict__ offs, const float* __restrict__ maskb,
    float* __restrict__ y)
{
    __shared__ float4 meta_w[576];
    __shared__ int4   meta_i[576];
    __shared__ __align__(16) ushort_t Bs[2][64][64];   // 128B rows, XOR swizzle

    int id = blockIdx.x;                  // b = id&7 == XCD -> xt slab L2-local
    int b = id & 7;
    int pxt = (id >> 3) & 15;
    int otile = id >> 7;                  // 0..1
    int p0 = pxt << 6;
    int t = threadIdx.x, lane = t & 63, wvid = t >> 6;
    int wm = wvid >> 1, wn = wvid & 1;
    int q4 = lane >> 4;

    // build-phase lane map: 16 threads = 64-ch span of ONE pixel-neighbor
    int bpx  = t >> 4;                    // 0..63 pixel
    int sub  = t & 15;                    // 0..15 -> 4-channel group (8B)
    int oct  = sub >> 1, half = sub & 1;
    const int wchunk = (oct ^ (bpx & 7)) * 8 + half * 4;   // ushort units

    // ---- bilinear metadata (64 px x 9 taps), byte offsets into xt rows ----
    for (int i = t; i < 576; i += 1024) {
        int k = i >> 6, j = i & 63;
        int hw = p0 + j, h = hw >> 5, w = hw & 31;
        float dy = offs[((b * 18 + 2 * k) << 10) + hw];
        float dx = offs[((b * 18 + 2 * k + 1) << 10) + hw];
        float m  = maskb[((b * 9 + k) << 10) + hw];
        float ys = dy + (float)(h + k / 3 - 1);
        float xs = dx + (float)(w + k % 3 - 1);
        float fy = floorf(ys), fx = floorf(xs);
        float wy = ys - fy, wx = xs - fx;
        int iy0 = (int)fy, ix0 = (int)fx;
        int iy1 = iy0 + 1, ix1 = ix0 + 1;
        float vy0 = (iy0 >= 0 && iy0 < 32) ? 1.f : 0.f;
        float vy1 = (iy1 >= 0 && iy1 < 32) ? 1.f : 0.f;
        float vx0 = (ix0 >= 0 && ix0 < 32) ? 1.f : 0.f;
        float vx1 = (ix1 >= 0 && ix1 < 32) ? 1.f : 0.f;
        int cy0 = min(max(iy0, 0), 31), cx0 = min(max(ix0, 0), 31);
        int cy1 = min(max(iy1, 0), 31), cx1 = min(max(ix1, 0), 31);
        float4 wv4;
        wv4.x = (1.f - wy) * (1.f - wx) * m * vy0 * vx0;
        wv4.y = (1.f - wy) * wx         * m * vy0 * vx1;
        wv4.z = wy         * (1.f - wx) * m * vy1 * vx0;
        wv4.w = wy         * wx         * m * vy1 * vx1;
        meta_w[i] = wv4;
        meta_i[i] = make_int4((cy0 * 32 + cx0) * 1536, (cy0 * 32 + cx1) * 1536,
                              (cy1 * 32 + cx0) * 1536, (cy1 * 32 + cx1) * 1536);
    }
    asm volatile("s_waitcnt lgkmcnt(0)" ::: "memory");
    __builtin_amdgcn_s_barrier();

    f32x4 acc[3][2];
#pragma unroll
    for (int f = 0; f < 3; ++f)
#pragma unroll
        for (int n = 0; n < 2; ++n) acc[f][n] = (f32x4){0.f, 0.f, 0.f, 0.f};

    const char* xb = (const char*)xt + (size_t)b * (HW * 1536);
    const int afrag0 = otile * 24 + wm * 3;

    s16x4 ga0, ga1, ga2, ga3, gb0, gb1, gb2, gb3;
    float4 w4a, w4b;

#define WBAR() do { asm volatile("s_waitcnt lgkmcnt(0)" ::: "memory"); \
                    __builtin_amdgcn_s_barrier(); } while (0)

#define ISSUE(G0, G1, G2, G3, W4, qq) do {                                  \
    int nt_ = (qq) / 12, nc_ = (qq) - nt_ * 12;                             \
    W4 = meta_w[nt_ * 64 + bpx];                                            \
    int4 i4_ = meta_i[nt_ * 64 + bpx];                                      \
    const char* bsrc_ = xb + nc_ * 128 + sub * 8;                           \
    G0 = *(const s16x4*)(bsrc_ + i4_.x);                                    \
    G1 = *(const s16x4*)(bsrc_ + i4_.y);                                    \
    G2 = *(const s16x4*)(bsrc_ + i4_.z);                                    \
    G3 = *(const s16x4*)(bsrc_ + i4_.w);                                    \
} while (0)

#define BUILD(G0, G1, G2, G3, W4, BUF) do {                                 \
    uint2 bw_;                                                              \
    unsigned r0_, r1_;                                                      \
    {                                                                       \
        float v0_ = W4.x * bf2f(G0[0]) + W4.y * bf2f(G1[0])                 \
                  + W4.z * bf2f(G2[0]) + W4.w * bf2f(G3[0]);                \
        float v1_ = W4.x * bf2f(G0[1]) + W4.y * bf2f(G1[1])                 \
                  + W4.z * bf2f(G2[1]) + W4.w * bf2f(G3[1]);                \
        asm("v_cvt_pk_bf16_f32 %0, %1, %2" : "=v"(r0_) : "v"(v0_), "v"(v1_)); \
    }                                                                       \
    {                                                                       \
        float v0_ = W4.x * bf2f(G0[2]) + W4.y * bf2f(G1[2])                 \
                  + W4.z * bf2f(G2[2]) + W4.w * bf2f(G3[2]);                \
        float v1_ = W4.x * bf2f(G0[3]) + W4.y * bf2f(G1[3])                 \
                  + W4.z * bf2f(G2[3]) + W4.w * bf2f(G3[3]);                \
        asm("v_cvt_pk_bf16_f32 %0, %1, %2" : "=v"(r1_) : "v"(v0_), "v"(v1_)); \
    }                                                                       \
    bw_.x = r0_; bw_.y = r1_;                                               \
    *(uint2*)&Bs[BUF][bpx][wchunk] = bw_;                                   \
} while (0)

#define MFMA_PHASE(P, BUF) do {                                             \
    __builtin_amdgcn_s_setprio(1);                                          \
    _Pragma("unroll")                                                       \
    for (int kk = 0; kk < 2; ++kk) {                                        \
        int s_ = 2 * (P) + kk;                                              \
        const s16x8* ap_ = (const s16x8*)(Amat +                            \
            ((size_t)(s_ * 48 + afrag0) * 64 + lane) * 8);                  \
        s16x8 a0_ = ap_[0], a1_ = ap_[64], a2_ = ap_[128];                  \
        int rc_ = ((kk * 4 + q4) ^ (lane & 7)) * 8;                         \
        s16x8 b0_ = *(const s16x8*)&Bs[BUF][wn * 32 + (lane & 15)][rc_];    \
        s16x8 b1_ = *(const s16x8*)&Bs[BUF][wn * 32 + 16 + (lane & 15)][rc_]; \
        acc[0][0] = __builtin_amdgcn_mfma_f32_16x16x32_bf16(a0_, b0_, acc[0][0], 0, 0, 0); \
        acc[0][1] = __builtin_amdgcn_mfma_f32_16x16x32_bf16(a0_, b1_, acc[0][1], 0, 0, 0); \
        acc[1][0] = __builtin_amdgcn_mfma_f32_16x16x32_bf16(a1_, b0_, acc[1][0], 0, 0, 0); \
        acc[1][1] = __builtin_amdgcn_mfma_f32_16x16x32_bf16(a1_, b1_, acc[1][1], 0, 0, 0); \
        acc[2][0] = __builtin_amdgcn_mfma_f32_16x16x32_bf16(a2_, b0_, acc[2][0], 0, 0, 0); \
        acc[2][1] = __builtin_amdgcn_mfma_f32_16x16x32_bf16(a2_, b1_, acc[2][1], 0, 0, 0); \
    }                                                                       \
    __builtin_amdgcn_s_setprio(0);                                          \
} while (0)

    // ---- prologue: gathers for phases 0 and 1; build phase 0 ----
    ISSUE(ga0, ga1, ga2, ga3, w4a, 0);
    ISSUE(gb0, gb1, gb2, gb3, w4b, 1);
    BUILD(ga0, ga1, ga2, ga3, w4a, 0);
    WBAR();

    // ---- main loop, unrolled by 2: even phases use set a, odd use set b ----
    for (int pp = 0; pp < 54; ++pp) {
        int pe = 2 * pp;
        if (pp < 53) ISSUE(ga0, ga1, ga2, ga3, w4a, pe + 2);
        MFMA_PHASE(pe, 0);
        BUILD(gb0, gb1, gb2, gb3, w4b, 1);      // phase pe+1 (always exists)
        WBAR();

        int po = pe + 1;
        if (pp < 53) ISSUE(gb0, gb1, gb2, gb3, w4b, po + 2);
        MFMA_PHASE(po, 1);
        if (pp < 53) BUILD(ga0, ga1, ga2, ga3, w4a, 0);   // phase po+1
        WBAR();
    }

    // ---- epilogue (no bias: per-channel bias cancels in batch-norm) ----
    int pxo = p0 + wn * 32 + (lane & 15);
    int obase = otile * 384 + wm * 48;
#pragma unroll
    for (int f = 0; f < 3; ++f) {
        int orow = obase + f * 16 + ((lane >> 4) << 2);
#pragma unroll
        for (int r = 0; r < 4; ++r) {
            size_t rowoff = ((size_t)(b * 768 + orow + r) << 10);
            y[rowoff + pxo]      = acc[f][0][r];
            y[rowoff + pxo + 16] = acc[f][1][r];
        }
    }
#undef WBAR
#undef ISSUE
#undef BUILD
#undef MFMA_PHASE
}

// ---------------------------------------------------------------------------
__global__ __launch_bounds__(256) void stats_kernel(
    const float* __restrict__ y, float* __restrict__ stats)
{
    int o = blockIdx.x;
    int tid = threadIdx.x;
    float s1 = 0.f, s2 = 0.f;
    for (int i = tid; i < B_N * HW; i += 256) {
        int b = i >> 10, hw = i & 1023;
        float v = y[(((size_t)b * 768 + o) << 10) + hw];
        s1 += v; s2 += v * v;
    }
#pragma unroll
    for (int off = 32; off > 0; off >>= 1) {
        s1 += __shfl_down(s1, off);
        s2 += __shfl_down(s2, off);
    }
    __shared__ float ls1[4], ls2[4];
    int wid = tid >> 6, lane = tid & 63;
    if (lane == 0) { ls1[wid] = s1; ls2[wid] = s2; }
    __syncthreads();
    if (tid == 0) {
        float t1 = ls1[0] + ls1[1] + ls1[2] + ls1[3];
        float t2 = ls2[0] + ls2[1] + ls2[2] + ls2[3];
        float mean = t1 * (1.0f / 8192.0f);
        float var  = t2 * (1.0f / 8192.0f) - mean * mean;
        stats[o]       = mean;
        stats[768 + o] = 1.0f / sqrtf(var + 1e-5f);
    }
}

__global__ __launch_bounds__(256) void finalize_kernel(
    const float* __restrict__ x, const float* __restrict__ stats,
    const float* __restrict__ gamma, const float* __restrict__ beta,
    float* __restrict__ y)
{
    const int total4 = B_N * 768 * HW / 4;
    for (int f = blockIdx.x * 256 + threadIdx.x; f < total4;
         f += gridDim.x * 256) {
        int e = f << 2;
        int o = (e >> 10) % 768;
        float mean = stats[o], rstd = stats[768 + o];
        float ga = gamma[o], be = beta[o];
        float4 v  = ((const float4*)y)[f];
        float4 xv = ((const float4*)x)[f];
        float4 r;
        {
            float yn = (v.x - mean) * rstd * ga + be;
            r.x = xv.x + 0.5f * yn * (1.0f + erff(yn * 0.70710678f));
        }
        {
            float yn = (v.y - mean) * rstd * ga + be;
            r.y = xv.y + 0.5f * yn * (1.0f + erff(yn * 0.70710678f));
        }
        {
            float yn = (v.z - mean) * rstd * ga + be;
            r.z = xv.z + 0.5f * yn * (1.0f + erff(yn * 0.70710678f));
        }
        {
            float yn = (v.w - mean) * rstd * ga + be;
            r.w = xv.w + 0.5f * yn * (1.0f + erff(yn * 0.70710678f));
        }
        ((float4*)y)[f] = r;
    }
}

// ---------------------------------------------------------------------------
extern "C" void kernel_launch(void* const* d_in, const int* in_sizes, int n_in,
                              void* d_out, int out_size, void* d_ws, size_t ws_size,
                              hipStream_t stream)
{
    const float* x        = (const float*)d_in[0];
    const float* proj_w   = (const float*)d_in[1];
    const float* offset_w = (const float*)d_in[3];
    const float* offset_b = (const float*)d_in[4];
    const float* mask_w   = (const float*)d_in[5];
    const float* mask_b   = (const float*)d_in[6];
    const float* gamma    = (const float*)d_in[7];
    const float* beta     = (const float*)d_in[8];

    char* ws = (char*)d_ws;
    float*    offs  = (float*)(ws);                  //   589824 B
    float*    maskb = (float*)(ws + 589824);         //   294912 B
    float*    stats = (float*)(ws + 884736);         //     6144 B
    ushort_t* A     = (ushort_t*)(ws + 890880);      // 10616832 B
    ushort_t* A2    = (ushort_t*)(ws + 11507712);    //   442368 B
    ushort_t* xt    = (ushort_t*)(ws + 11950080);    // 12582912 B  (tot ~24.5MB)
    float* y = (float*)d_out;

    prepack_xt<<<1536, 256, 0, stream>>>(x, xt);
    prepack_om<<<108, 256, 0, stream>>>(offset_w, mask_w, A2);
    prepack_proj<<<2592, 256, 0, stream>>>(proj_w, A);
    offmask_mfma<<<256, 256, 0, stream>>>(xt, A2, offset_b, mask_b, offs, maskb);
    deform_mfma<<<256, 1024, 0, stream>>>(xt, A, offs, maskb, y);
    stats_kernel<<<768, 256, 0, stream>>>(y, stats);
    finalize_kernel<<<2048, 256, 0, stream>>>(x, stats, gamma, beta, y);
}

// Round 7
// 262.904 us; speedup vs baseline: 1.1652x; 1.1652x over previous
//
#include <hip/hip_runtime.h>
#include <math.h>

typedef __attribute__((ext_vector_type(4))) float f32x4;
typedef __attribute__((ext_vector_type(8))) short s16x8;
typedef unsigned short ushort_t;

#define HW   1024
#define C_IN 768
#define B_N  8

__device__ inline ushort_t f2bf(float f) {
    unsigned u = __builtin_bit_cast(unsigned, f);
    unsigned r = u + 0x7FFFu + ((u >> 16) & 1u);
    return (ushort_t)(r >> 16);
}
__device__ inline float bf2f(short s) {
    return __builtin_bit_cast(float, ((unsigned)(ushort_t)s) << 16);
}

// ---------------------------------------------------------------------------
// x [b][c][pos] fp32  ->  xt [b][pos][c] bf16   (row = 768 ch = 1536 B)
// ---------------------------------------------------------------------------
__global__ __launch_bounds__(256) void prepack_xt(
    const float* __restrict__ x, ushort_t* __restrict__ xt)
{
    __shared__ ushort_t tile[64][66];
    int bid = blockIdx.x;                 // 8 * 12 * 16
    int b  = bid / 192;
    int r  = bid % 192;
    int cg = r / 16, pg = r % 16;
    int c0 = cg * 64, p0 = pg * 64;
    int t = threadIdx.x;
#pragma unroll
    for (int i = 0; i < 16; ++i) {
        int idx = t + i * 256;
        int cr = idx >> 6, col = idx & 63;
        tile[cr][col] = f2bf(x[(((size_t)b * C_IN + c0 + cr) << 10) + p0 + col]);
    }
    __syncthreads();
#pragma unroll
    for (int i = 0; i < 16; ++i) {
        int idx = t + i * 256;
        int pr = idx >> 6, col = idx & 63;
        xt[((size_t)(b << 10) + p0 + pr) * C_IN + c0 + col] = tile[col][pr];
    }
}

// ---------------------------------------------------------------------------
// proj_w -> MFMA A-frag layout, k = tap*768 + c (tap-major).
// ---------------------------------------------------------------------------
__global__ __launch_bounds__(256) void prepack_proj(
    const float* __restrict__ pw, ushort_t* __restrict__ A)
{
    int t = blockIdx.x * 256 + threadIdx.x;     // 216*48*64 threads
    int lane = t & 63;
    int smi  = t >> 6;
    int s  = smi / 48, mf = smi - s * 48;
    int o  = mf * 16 + (lane & 15);
    int k0 = s * 32 + ((lane >> 4) << 3);
    int tap = k0 / 768;
    int c   = k0 - tap * 768;
    const float* src = pw + (size_t)o * 6912 + (size_t)c * 9 + tap;
    s16x8 pk;
#pragma unroll
    for (int e = 0; e < 8; ++e) pk[e] = (short)f2bf(src[e * 9]);
    *(s16x8*)(A + (size_t)smi * 512 + lane * 8) = pk;
}

__global__ __launch_bounds__(256) void prepack_om(
    const float* __restrict__ offw, const float* __restrict__ mskw,
    ushort_t* __restrict__ A2)
{
    int t = blockIdx.x * 256 + threadIdx.x;     // 216*2*64 threads
    int lane = t & 63;
    int smi  = t >> 6;
    int s  = smi >> 1, mf = smi & 1;
    int oc = mf * 16 + (lane & 15);
    int k0 = s * 32 + ((lane >> 4) << 3);
    int tap = k0 / 768;
    int c   = k0 - tap * 768;
    s16x8 pk;
#pragma unroll
    for (int e = 0; e < 8; ++e) pk[e] = 0;
    if (oc < 27) {
        const float* src = (oc < 18)
            ? offw + ((size_t)oc        * 768 + c) * 9 + tap
            : mskw + ((size_t)(oc - 18) * 768 + c) * 9 + tap;
#pragma unroll
        for (int e = 0; e < 8; ++e) pk[e] = (short)f2bf(src[e * 9]);
    }
    *(s16x8*)(A2 + (size_t)smi * 512 + lane * 8) = pk;
}

// ---------------------------------------------------------------------------
// Offset/mask conv: LDS-free MFMA GEMM. B-frags are 16B contiguous in xt.
// ---------------------------------------------------------------------------
__global__ __launch_bounds__(256) void offmask_mfma(
    const ushort_t* __restrict__ xt, const ushort_t* __restrict__ A2,
    const float* __restrict__ offb, const float* __restrict__ mbias,
    float* __restrict__ offs, float* __restrict__ maskb)
{
    int bid = blockIdx.x;               // b*32 + pt
    int b = bid >> 5, pt = bid & 31;
    int p0 = pt << 5;
    int t = threadIdx.x, lane = t & 63, wv = t >> 6;
    int mf = wv >> 1, nf = wv & 1;
    int q = lane >> 4;
    int px = p0 + nf * 16 + (lane & 15);
    int h = px >> 5, w = px & 31;
    const char* xb = (const char*)xt + (size_t)b * (HW * 1536);
    f32x4 acc = (f32x4){0.f, 0.f, 0.f, 0.f};

    for (int tap = 0; tap < 9; ++tap) {
        int yy = h + tap / 3 - 1, xx = w + tap % 3 - 1;
        bool ok = (yy >= 0 && yy < 32 && xx >= 0 && xx < 32);
        int pos = ok ? (yy * 32 + xx) : 0;
        const char* bp = xb + (size_t)pos * 1536 + q * 16;
        for (int cs = 0; cs < 24; ++cs) {
            int s = tap * 24 + cs;
            s16x8 bf;
            if (ok) bf = *(const s16x8*)(bp + cs * 64);
            else    bf = (s16x8){0, 0, 0, 0, 0, 0, 0, 0};
            s16x8 af = *(const s16x8*)(A2 + ((size_t)(s * 2 + mf) * 64 + lane) * 8);
            acc = __builtin_amdgcn_mfma_f32_16x16x32_bf16(af, bf, acc, 0, 0, 0);
        }
    }
#pragma unroll
    for (int r = 0; r < 4; ++r) {
        int oc = mf * 16 + ((lane >> 4) << 2) + r;
        if (oc < 18) {
            float v = acc[r] + offb[oc];
            v = fminf(fmaxf(v, -8.f), 8.f);        // max_off = 32//4
            offs[((b * 18 + oc) << 10) + px] = v;
        } else if (oc < 27) {
            float v = acc[r] + mbias[oc - 18];
            maskb[((b * 9 + oc - 18) << 10) + px] = 2.f / (1.f + expf(-v));
        }
    }
}

// ---------------------------------------------------------------------------
// Deformable conv GEMM, tile 192(o) x 64(px), 8 waves (4 wm x 2 wn).
// 108 phases of 64 channels x 1 tap. Depth-2 gather prefetch AND register
// double-buffered A-frag prefetch (phase p+1's 6 A-frags load during phase
// p's MFMAs). Weak barriers (lgkmcnt(0)+s_barrier; vmcnt stays in flight),
// Bs rows exactly 128B so the XOR chunk swizzle is 2-way (free).
// ---------------------------------------------------------------------------
__global__ __launch_bounds__(512, 4) void deform_mfma(
    const ushort_t* __restrict__ xt, const ushort_t* __restrict__ Amat,
    const float* __restrict__ offs, const float* __restrict__ maskb,
    float* __restrict__ y)
{
    __shared__ float4 meta_w[576];
    __shared__ int4   meta_i[576];
    __shared__ __align__(16) ushort_t Bs[2][64][64];   // 128B rows, XOR swizzle

    int id = blockIdx.x;                  // b = id&7 == XCD -> xt slab L2-local
    int b = id & 7;
    int pxt = (id >> 3) & 15;
    int otile = id >> 7;
    int p0 = pxt << 6;
    int t = threadIdx.x, lane = t & 63, wv = t >> 6;
    int wm = wv >> 1, wn = wv & 1;
    int q4 = lane >> 4;

    // build-phase lane map: 8 lanes = 64-ch span of ONE pixel-neighbor
    int bpx = wv * 8 + (lane >> 3);       // 0..63 pixel
    int oct = lane & 7;                   // 0..7 channel-octet (16B)
    const int wchunk = (oct ^ (bpx & 7)) * 8;

    // ---- bilinear metadata (64 px x 9 taps), byte offsets into xt rows ----
    for (int i = t; i < 576; i += 512) {
        int k = i >> 6, j = i & 63;
        int hw = p0 + j, h = hw >> 5, w = hw & 31;
        float dy = offs[((b * 18 + 2 * k) << 10) + hw];
        float dx = offs[((b * 18 + 2 * k + 1) << 10) + hw];
        float m  = maskb[((b * 9 + k) << 10) + hw];
        float ys = dy + (float)(h + k / 3 - 1);
        float xs = dx + (float)(w + k % 3 - 1);
        float fy = floorf(ys), fx = floorf(xs);
        float wy = ys - fy, wx = xs - fx;
        int iy0 = (int)fy, ix0 = (int)fx;
        int iy1 = iy0 + 1, ix1 = ix0 + 1;
        float vy0 = (iy0 >= 0 && iy0 < 32) ? 1.f : 0.f;
        float vy1 = (iy1 >= 0 && iy1 < 32) ? 1.f : 0.f;
        float vx0 = (ix0 >= 0 && ix0 < 32) ? 1.f : 0.f;
        float vx1 = (ix1 >= 0 && ix1 < 32) ? 1.f : 0.f;
        int cy0 = min(max(iy0, 0), 31), cx0 = min(max(ix0, 0), 31);
        int cy1 = min(max(iy1, 0), 31), cx1 = min(max(ix1, 0), 31);
        float4 wv4;
        wv4.x = (1.f - wy) * (1.f - wx) * m * vy0 * vx0;
        wv4.y = (1.f - wy) * wx         * m * vy0 * vx1;
        wv4.z = wy         * (1.f - wx) * m * vy1 * vx0;
        wv4.w = wy         * wx         * m * vy1 * vx1;
        meta_w[i] = wv4;
        meta_i[i] = make_int4((cy0 * 32 + cx0) * 1536, (cy0 * 32 + cx1) * 1536,
                              (cy1 * 32 + cx0) * 1536, (cy1 * 32 + cx1) * 1536);
    }
    asm volatile("s_waitcnt lgkmcnt(0)" ::: "memory");
    __builtin_amdgcn_s_barrier();

    f32x4 acc[3][2];
#pragma unroll
    for (int f = 0; f < 3; ++f)
#pragma unroll
        for (int n = 0; n < 2; ++n) acc[f][n] = (f32x4){0.f, 0.f, 0.f, 0.f};

    const char* xb = (const char*)xt + (size_t)b * (HW * 1536);
    const int afrag0 = otile * 12 + wm * 3;

    s16x8 ga0, ga1, ga2, ga3, gb0, gb1, gb2, gb3;
    float4 w4a, w4b;
    // A-frag double buffer: set X feeds even phases, set Y odd phases
    s16x8 xA0, xA1, xA2, xA3, xA4, xA5;
    s16x8 yA0, yA1, yA2, yA3, yA4, yA5;

#define WBAR() do { asm volatile("s_waitcnt lgkmcnt(0)" ::: "memory"); \
                    __builtin_amdgcn_s_barrier(); } while (0)

#define ISSUE(G0, G1, G2, G3, W4, qq) do {                                  \
    int nt_ = (qq) / 12, nc_ = (qq) - nt_ * 12;                             \
    W4 = meta_w[nt_ * 64 + bpx];                                            \
    int4 i4_ = meta_i[nt_ * 64 + bpx];                                      \
    const char* bsrc_ = xb + nc_ * 128 + oct * 16;                          \
    G0 = *(const s16x8*)(bsrc_ + i4_.x);                                    \
    G1 = *(const s16x8*)(bsrc_ + i4_.y);                                    \
    G2 = *(const s16x8*)(bsrc_ + i4_.z);                                    \
    G3 = *(const s16x8*)(bsrc_ + i4_.w);                                    \
} while (0)

#define LOAD_A(A0, A1, A2, A3, A4, A5, P) do {                              \
    const s16x8* ap0_ = (const s16x8*)(Amat +                               \
        ((size_t)((2 * (P)) * 48 + afrag0) * 64 + lane) * 8);               \
    A0 = ap0_[0]; A1 = ap0_[64]; A2 = ap0_[128];                            \
    const s16x8* ap1_ = (const s16x8*)(Amat +                               \
        ((size_t)((2 * (P) + 1) * 48 + afrag0) * 64 + lane) * 8);           \
    A3 = ap1_[0]; A4 = ap1_[64]; A5 = ap1_[128];                            \
} while (0)

#define BUILD(G0, G1, G2, G3, W4, BUF) do {                                 \
    uint2 bw_;                                                              \
    unsigned r0_, r1_;                                                      \
    {                                                                       \
        float v0_ = W4.x * bf2f(G0[0]) + W4.y * bf2f(G1[0])                 \
                  + W4.z * bf2f(G2[0]) + W4.w * bf2f(G3[0]);                \
        float v1_ = W4.x * bf2f(G0[1]) + W4.y * bf2f(G1[1])                 \
                  + W4.z * bf2f(G2[1]) + W4.w * bf2f(G3[1]);                \
        asm("v_cvt_pk_bf16_f32 %0, %1, %2" : "=v"(r0_) : "v"(v0_), "v"(v1_)); \
    }                                                                       \
    {                                                                       \
        float v0_ = W4.x * bf2f(G0[2]) + W4.y * bf2f(G1[2])                 \
                  + W4.z * bf2f(G2[2]) + W4.w * bf2f(G3[2]);                \
        float v1_ = W4.x * bf2f(G0[3]) + W4.y * bf2f(G1[3])                 \
                  + W4.z * bf2f(G2[3]) + W4.w * bf2f(G3[3]);                \
        asm("v_cvt_pk_bf16_f32 %0, %1, %2" : "=v"(r1_) : "v"(v0_), "v"(v1_)); \
    }                                                                       \
    bw_.x = r0_; bw_.y = r1_;                                               \
    *(uint2*)((ushort_t*)&Bs[BUF][bpx][wchunk]) = bw_;                      \
    {                                                                       \
        uint2 bw2_;                                                         \
        unsigned r2_, r3_;                                                  \
        {                                                                   \
            float v0_ = W4.x * bf2f(G0[4]) + W4.y * bf2f(G1[4])             \
                      + W4.z * bf2f(G2[4]) + W4.w * bf2f(G3[4]);            \
            float v1_ = W4.x * bf2f(G0[5]) + W4.y * bf2f(G1[5])             \
                      + W4.z * bf2f(G2[5]) + W4.w * bf2f(G3[5]);            \
            asm("v_cvt_pk_bf16_f32 %0, %1, %2" : "=v"(r2_) : "v"(v0_), "v"(v1_)); \
        }                                                                   \
        {                                                                   \
            float v0_ = W4.x * bf2f(G0[6]) + W4.y * bf2f(G1[6])             \
                      + W4.z * bf2f(G2[6]) + W4.w * bf2f(G3[6]);            \
            float v1_ = W4.x * bf2f(G0[7]) + W4.y * bf2f(G1[7])             \
                      + W4.z * bf2f(G2[7]) + W4.w * bf2f(G3[7]);            \
            asm("v_cvt_pk_bf16_f32 %0, %1, %2" : "=v"(r3_) : "v"(v0_), "v"(v1_)); \
        }                                                                   \
        bw2_.x = r2_; bw2_.y = r3_;                                         \
        *(uint2*)((ushort_t*)&Bs[BUF][bpx][wchunk] + 4) = bw2_;             \
    }                                                                       \
} while (0)

#define MFMA_PHASE(BUF, A0, A1, A2, A3, A4, A5) do {                        \
    {                                                                       \
        int rc_ = ((0 * 4 + q4) ^ (lane & 7)) * 8;                          \
        s16x8 b0_ = *(const s16x8*)&Bs[BUF][wn * 32 + (lane & 15)][rc_];    \
        s16x8 b1_ = *(const s16x8*)&Bs[BUF][wn * 32 + 16 + (lane & 15)][rc_]; \
        acc[0][0] = __builtin_amdgcn_mfma_f32_16x16x32_bf16(A0, b0_, acc[0][0], 0, 0, 0); \
        acc[0][1] = __builtin_amdgcn_mfma_f32_16x16x32_bf16(A0, b1_, acc[0][1], 0, 0, 0); \
        acc[1][0] = __builtin_amdgcn_mfma_f32_16x16x32_bf16(A1, b0_, acc[1][0], 0, 0, 0); \
        acc[1][1] = __builtin_amdgcn_mfma_f32_16x16x32_bf16(A1, b1_, acc[1][1], 0, 0, 0); \
        acc[2][0] = __builtin_amdgcn_mfma_f32_16x16x32_bf16(A2, b0_, acc[2][0], 0, 0, 0); \
        acc[2][1] = __builtin_amdgcn_mfma_f32_16x16x32_bf16(A2, b1_, acc[2][1], 0, 0, 0); \
    }                                                                       \
    {                                                                       \
        int rc_ = ((1 * 4 + q4) ^ (lane & 7)) * 8;                          \
        s16x8 b0_ = *(const s16x8*)&Bs[BUF][wn * 32 + (lane & 15)][rc_];    \
        s16x8 b1_ = *(const s16x8*)&Bs[BUF][wn * 32 + 16 + (lane & 15)][rc_]; \
        acc[0][0] = __builtin_amdgcn_mfma_f32_16x16x32_bf16(A3, b0_, acc[0][0], 0, 0, 0); \
        acc[0][1] = __builtin_amdgcn_mfma_f32_16x16x32_bf16(A3, b1_, acc[0][1], 0, 0, 0); \
        acc[1][0] = __builtin_amdgcn_mfma_f32_16x16x32_bf16(A4, b0_, acc[1][0], 0, 0, 0); \
        acc[1][1] = __builtin_amdgcn_mfma_f32_16x16x32_bf16(A4, b1_, acc[1][1], 0, 0, 0); \
        acc[2][0] = __builtin_amdgcn_mfma_f32_16x16x32_bf16(A5, b0_, acc[2][0], 0, 0, 0); \
        acc[2][1] = __builtin_amdgcn_mfma_f32_16x16x32_bf16(A5, b1_, acc[2][1], 0, 0, 0); \
    }                                                                       \
} while (0)

    // ---- prologue: gathers for phases 0,1; A for phase 0; build phase 0 ----
    ISSUE(ga0, ga1, ga2, ga3, w4a, 0);
    ISSUE(gb0, gb1, gb2, gb3, w4b, 1);
    LOAD_A(xA0, xA1, xA2, xA3, xA4, xA5, 0);
    BUILD(ga0, ga1, ga2, ga3, w4a, 0);
    WBAR();

    // ---- main loop, unrolled by 2: even phases use set a/X, odd b/Y ----
    for (int pp = 0; pp < 54; ++pp) {
        int pe = 2 * pp;
        if (pp < 53) ISSUE(ga0, ga1, ga2, ga3, w4a, pe + 2);
        LOAD_A(yA0, yA1, yA2, yA3, yA4, yA5, pe + 1);   // prefetch A (odd phase)
        MFMA_PHASE(0, xA0, xA1, xA2, xA3, xA4, xA5);
        BUILD(gb0, gb1, gb2, gb3, w4b, 1);              // phase pe+1 B-tile
        WBAR();

        int po = pe + 1;
        if (pp < 53) {
            ISSUE(gb0, gb1, gb2, gb3, w4b, po + 2);
            LOAD_A(xA0, xA1, xA2, xA3, xA4, xA5, po + 1); // prefetch A (even)
        }
        MFMA_PHASE(1, yA0, yA1, yA2, yA3, yA4, yA5);
        if (pp < 53) BUILD(ga0, ga1, ga2, ga3, w4a, 0); // phase po+1 B-tile
        WBAR();
    }

    // ---- epilogue (no bias: per-channel bias cancels in batch-norm) ----
    int pxo = p0 + wn * 32 + (lane & 15);
    int obase = otile * 192 + wm * 48;
#pragma unroll
    for (int f = 0; f < 3; ++f) {
        int orow = obase + f * 16 + ((lane >> 4) << 2);
#pragma unroll
        for (int r = 0; r < 4; ++r) {
            size_t rowoff = ((size_t)(b * 768 + orow + r) << 10);
            y[rowoff + pxo]      = acc[f][0][r];
            y[rowoff + pxo + 16] = acc[f][1][r];
        }
    }
#undef WBAR
#undef ISSUE
#undef LOAD_A
#undef BUILD
#undef MFMA_PHASE
}

// ---------------------------------------------------------------------------
__global__ __launch_bounds__(256) void stats_kernel(
    const float* __restrict__ y, float* __restrict__ stats)
{
    int o = blockIdx.x;
    int tid = threadIdx.x;
    float s1 = 0.f, s2 = 0.f;
    for (int i = tid; i < B_N * HW; i += 256) {
        int b = i >> 10, hw = i & 1023;
        float v = y[(((size_t)b * 768 + o) << 10) + hw];
        s1 += v; s2 += v * v;
    }
#pragma unroll
    for (int off = 32; off > 0; off >>= 1) {
        s1 += __shfl_down(s1, off);
        s2 += __shfl_down(s2, off);
    }
    __shared__ float ls1[4], ls2[4];
    int wid = tid >> 6, lane = tid & 63;
    if (lane == 0) { ls1[wid] = s1; ls2[wid] = s2; }
    __syncthreads();
    if (tid == 0) {
        float t1 = ls1[0] + ls1[1] + ls1[2] + ls1[3];
        float t2 = ls2[0] + ls2[1] + ls2[2] + ls2[3];
        float mean = t1 * (1.0f / 8192.0f);
        float var  = t2 * (1.0f / 8192.0f) - mean * mean;
        stats[o]       = mean;
        stats[768 + o] = 1.0f / sqrtf(var + 1e-5f);
    }
}

__global__ __launch_bounds__(256) void finalize_kernel(
    const float* __restrict__ x, const float* __restrict__ stats,
    const float* __restrict__ gamma, const float* __restrict__ beta,
    float* __restrict__ y)
{
    const int total4 = B_N * 768 * HW / 4;
    for (int f = blockIdx.x * 256 + threadIdx.x; f < total4;
         f += gridDim.x * 256) {
        int e = f << 2;
        int o = (e >> 10) % 768;
        float mean = stats[o], rstd = stats[768 + o];
        float ga = gamma[o], be = beta[o];
        float4 v  = ((const float4*)y)[f];
        float4 xv = ((const float4*)x)[f];
        float4 r;
        {
            float yn = (v.x - mean) * rstd * ga + be;
            r.x = xv.x + 0.5f * yn * (1.0f + erff(yn * 0.70710678f));
        }
        {
            float yn = (v.y - mean) * rstd * ga + be;
            r.y = xv.y + 0.5f * yn * (1.0f + erff(yn * 0.70710678f));
        }
        {
            float yn = (v.z - mean) * rstd * ga + be;
            r.z = xv.z + 0.5f * yn * (1.0f + erff(yn * 0.70710678f));
        }
        {
            float yn = (v.w - mean) * rstd * ga + be;
            r.w = xv.w + 0.5f * yn * (1.0f + erff(yn * 0.70710678f));
        }
        ((float4*)y)[f] = r;
    }
}

// ---------------------------------------------------------------------------
extern "C" void kernel_launch(void* const* d_in, const int* in_sizes, int n_in,
                              void* d_out, int out_size, void* d_ws, size_t ws_size,
                              hipStream_t stream)
{
    const float* x        = (const float*)d_in[0];
    const float* proj_w   = (const float*)d_in[1];
    const float* offset_w = (const float*)d_in[3];
    const float* offset_b = (const float*)d_in[4];
    const float* mask_w   = (const float*)d_in[5];
    const float* mask_b   = (const float*)d_in[6];
    const float* gamma    = (const float*)d_in[7];
    const float* beta     = (const float*)d_in[8];

    char* ws = (char*)d_ws;
    float*    offs  = (float*)(ws);                  //   589824 B
    float*    maskb = (float*)(ws + 589824);         //   294912 B
    float*    stats = (float*)(ws + 884736);         //     6144 B
    ushort_t* A     = (ushort_t*)(ws + 890880);      // 10616832 B
    ushort_t* A2    = (ushort_t*)(ws + 11507712);    //   442368 B
    ushort_t* xt    = (ushort_t*)(ws + 11950080);    // 12582912 B  (tot ~24.5MB)
    float* y = (float*)d_out;

    prepack_xt<<<1536, 256, 0, stream>>>(x, xt);
    prepack_om<<<108, 256, 0, stream>>>(offset_w, mask_w, A2);
    prepack_proj<<<2592, 256, 0, stream>>>(proj_w, A);
    offmask_mfma<<<256, 256, 0, stream>>>(xt, A2, offset_b, mask_b, offs, maskb);
    deform_mfma<<<512, 512, 0, stream>>>(xt, A, offs, maskb, y);
    stats_kernel<<<768, 256, 0, stream>>>(y, stats);
    finalize_kernel<<<2048, 256, 0, stream>>>(x, stats, gamma, beta, y);
}